// Round 7
// baseline (939.710 us; speedup 1.0000x reference)
//
#include <hip/hip_runtime.h>
#include <hip/hip_bf16.h>
#include <math.h>

// Problem constants
#define HH 128
#define WWW 128
#define BB 8
#define MM (HH*WWW*BB)      // 131072 rows (h,w,b)

typedef unsigned int u32;
typedef unsigned short u16;

__device__ __forceinline__ float b2f(u16 s){ return __uint_as_float(((u32)s)<<16); }
__device__ __forceinline__ u16 f2b(float f){
    u32 u = __float_as_uint(f);
    return (u16)((u + 0x7fffu + ((u>>16)&1u)) >> 16);
}

// ---------------- K0: trig tables only --------------------------------------
__global__ __launch_bounds__(128) void k_prep(const float* __restrict__ th_f,
                                              const float* __restrict__ th_r,
                                              float* __restrict__ trig)
{
    int d = threadIdx.x;          // 128 threads, 1 block
    trig[d]     = cosf(th_f[d]); trig[128+d] = sinf(th_f[d]);
    trig[256+d] = cosf(th_r[d]); trig[384+d] = sinf(th_r[d]);
}

// ---------------- K1: front half in FULL F32 --------------------------------
// HALF h: IH[m][0..128) = silu(x @ W_in[:,128h:128h+128] + b_in)   (f32, d_out)
//         OMH[m][0..64) = 1 - sigmoid(x @ W_lam[:,64h:64h+64] + b_lam) (f32, ws)
template<int HALF>
__global__ __launch_bounds__(256) void k_front_f32(
    const float* __restrict__ x, const float* __restrict__ W_in,
    const float* __restrict__ b_in, const float* __restrict__ W_lam,
    const float* __restrict__ b_lam, float* __restrict__ IH,
    float* __restrict__ OMH)
{
    __shared__ float xs_t[128][64];   // 32 KiB  [k][r]
    __shared__ float wt[128][64];     // 32 KiB  [k][c]
    int tid = threadIdx.x;
    int m0 = blockIdx.x * 64;         // 2048 blocks

    #pragma unroll
    for (int it = 0; it < 8; ++it) {  // stage x transposed: 64 rows x 128 k
        int u = it*256 + tid;
        int r = u >> 5, c4 = u & 31;
        float4 v = *(const float4*)(x + (size_t)(m0+r)*128 + c4*4);
        xs_t[c4*4+0][r] = v.x; xs_t[c4*4+1][r] = v.y;
        xs_t[c4*4+2][r] = v.z; xs_t[c4*4+3][r] = v.w;
    }

    int ri = tid >> 4, ci = tid & 15;

    for (int nc = 0; nc < 3; ++nc) {
        __syncthreads();
        #pragma unroll
        for (int it = 0; it < 32; ++it) {     // stage W chunk: 128k x 64c
            int u = it*256 + tid;
            int k = u >> 6, c = u & 63;
            wt[k][c] = (nc < 2) ? W_in[k*256 + 128*HALF + nc*64 + c]
                                : W_lam[k*128 + 64*HALF + c];
        }
        __syncthreads();

        float acc[4][4] = {};
        #pragma unroll 8
        for (int k = 0; k < 128; ++k) {
            float4 xv = *(const float4*)(&xs_t[k][ri*4]);
            float4 wv = *(const float4*)(&wt[k][ci*4]);
            acc[0][0] = fmaf(xv.x, wv.x, acc[0][0]);
            acc[0][1] = fmaf(xv.x, wv.y, acc[0][1]);
            acc[0][2] = fmaf(xv.x, wv.z, acc[0][2]);
            acc[0][3] = fmaf(xv.x, wv.w, acc[0][3]);
            acc[1][0] = fmaf(xv.y, wv.x, acc[1][0]);
            acc[1][1] = fmaf(xv.y, wv.y, acc[1][1]);
            acc[1][2] = fmaf(xv.y, wv.z, acc[1][2]);
            acc[1][3] = fmaf(xv.y, wv.w, acc[1][3]);
            acc[2][0] = fmaf(xv.z, wv.x, acc[2][0]);
            acc[2][1] = fmaf(xv.z, wv.y, acc[2][1]);
            acc[2][2] = fmaf(xv.z, wv.z, acc[2][2]);
            acc[2][3] = fmaf(xv.z, wv.w, acc[2][3]);
            acc[3][0] = fmaf(xv.w, wv.x, acc[3][0]);
            acc[3][1] = fmaf(xv.w, wv.y, acc[3][1]);
            acc[3][2] = fmaf(xv.w, wv.z, acc[3][2]);
            acc[3][3] = fmaf(xv.w, wv.w, acc[3][3]);
        }

        #pragma unroll
        for (int i = 0; i < 4; ++i) {
            int m = m0 + ri*4 + i;
            #pragma unroll
            for (int j = 0; j < 4; ++j) {
                int cc = ci*4 + j;
                if (nc < 2) {
                    float v = acc[i][j] + b_in[128*HALF + nc*64 + cc];
                    float e = __expf(-v);
                    IH[(size_t)m*128 + nc*64 + cc] = v/(1.f+e);    // silu
                } else {
                    float v = acc[i][j] + b_lam[64*HALF + cc];
                    float e = __expf(-v);
                    OMH[(size_t)m*64 + cc] = e/(1.f+e);            // 1-sigmoid
                }
            }
        }
    }
}

// ---------------- K2: streaming complex scans, fully F32 --------------------
template<int AXISW, int REV, int ACCUM, int HALF>
__global__ __launch_bounds__(256) void k_scan(const float* __restrict__ IH,
                                              const float* __restrict__ OMH,
                                              const float* __restrict__ trig,
                                              float2* __restrict__ P)
{
    int j = blockIdx.x*256 + threadIdx.x;  // 65536 columns (this half)
    int dl = j & 63;
    int col = j >> 6;                      // 0..1023
    int rowbase, stride;
    if (AXISW) { rowbase = (col>>3)*1024 + (col&7); stride = 8; }
    else       { rowbase = col;                     stride = 1024; }

    int dg = 64*HALF + dl;
    const float* ct = trig + (REV ? 256 : 0);
    float cf = ct[dg], sf = ct[128+dg];

    long long row  = (long long)rowbase + (long long)stride*(REV ? 127 : 0);
    long long rstep = (long long)stride * (REV ? -1 : 1);

    float hr = 0.f, hi = 0.f;
    #pragma unroll 4
    for (int t = 0; t < 128; ++t, row += rstep) {
        float2 in2 = *(const float2*)(IH + row*128 + 2*dl);
        float om  = OMH[row*64 + dl];
        float lam = 1.f - om;
        float gr = lam*cf, gi = lam*sf;
        float nr = fmaf(gr, hr, fmaf(-gi, hi, om*in2.x));
        float ni = fmaf(gr, hi, fmaf( gi, hr, om*in2.y));
        hr = nr; hi = ni;
        long long pi = row*128 + dg;
        float2 o;
        if (ACCUM) {
            o = P[pi];
            o.x += hr; o.y += hi;
        } else {
            o.x = hr; o.y = hi;
        }
        P[pi] = o;
    }
}

// ---------------- K3: gate GEMM in FULL F32 (bf16 store only) ---------------
// GATE[m][n] = silu(x @ W_gate + b_gate), natural column order n=0..255
__global__ __launch_bounds__(256) void k_gate_f32(
    const float* __restrict__ x, const float* __restrict__ W_gate,
    const float* __restrict__ b_gate, u16* __restrict__ GATE)
{
    __shared__ float xs_t[128][64];
    __shared__ float wt[128][64];
    int tid = threadIdx.x;
    int m0 = blockIdx.x * 64;         // 2048 blocks

    #pragma unroll
    for (int it = 0; it < 8; ++it) {
        int u = it*256 + tid;
        int r = u >> 5, c4 = u & 31;
        float4 v = *(const float4*)(x + (size_t)(m0+r)*128 + c4*4);
        xs_t[c4*4+0][r] = v.x; xs_t[c4*4+1][r] = v.y;
        xs_t[c4*4+2][r] = v.z; xs_t[c4*4+3][r] = v.w;
    }

    int ri = tid >> 4, ci = tid & 15;

    for (int nc = 0; nc < 4; ++nc) {
        __syncthreads();
        #pragma unroll
        for (int it = 0; it < 32; ++it) {
            int u = it*256 + tid;
            int k = u >> 6, c = u & 63;
            wt[k][c] = W_gate[k*256 + nc*64 + c];
        }
        __syncthreads();

        float acc[4][4] = {};
        #pragma unroll 8
        for (int k = 0; k < 128; ++k) {
            float4 xv = *(const float4*)(&xs_t[k][ri*4]);
            float4 wv = *(const float4*)(&wt[k][ci*4]);
            acc[0][0] = fmaf(xv.x, wv.x, acc[0][0]);
            acc[0][1] = fmaf(xv.x, wv.y, acc[0][1]);
            acc[0][2] = fmaf(xv.x, wv.z, acc[0][2]);
            acc[0][3] = fmaf(xv.x, wv.w, acc[0][3]);
            acc[1][0] = fmaf(xv.y, wv.x, acc[1][0]);
            acc[1][1] = fmaf(xv.y, wv.y, acc[1][1]);
            acc[1][2] = fmaf(xv.y, wv.z, acc[1][2]);
            acc[1][3] = fmaf(xv.y, wv.w, acc[1][3]);
            acc[2][0] = fmaf(xv.z, wv.x, acc[2][0]);
            acc[2][1] = fmaf(xv.z, wv.y, acc[2][1]);
            acc[2][2] = fmaf(xv.z, wv.z, acc[2][2]);
            acc[2][3] = fmaf(xv.z, wv.w, acc[2][3]);
            acc[3][0] = fmaf(xv.w, wv.x, acc[3][0]);
            acc[3][1] = fmaf(xv.w, wv.y, acc[3][1]);
            acc[3][2] = fmaf(xv.w, wv.z, acc[3][2]);
            acc[3][3] = fmaf(xv.w, wv.w, acc[3][3]);
        }

        #pragma unroll
        for (int i = 0; i < 4; ++i) {
            int m = m0 + ri*4 + i;
            #pragma unroll
            for (int j = 0; j < 4; ++j) {
                int n = nc*64 + ci*4 + j;
                float v = acc[i][j] + b_gate[n];
                float e = __expf(-v);
                GATE[(size_t)m*256 + n] = f2b(v/(1.f+e));
            }
        }
    }
}

// ---------------- K4: LN + gate + out GEMM, FULL F32, no permutation --------
#define GETC(v,i) ((i)==0?(v).x:(i)==1?(v).y:(i)==2?(v).z:(v).w)
__global__ __launch_bounds__(256) void k_backend_f32(
    const float4* __restrict__ Pf, const u16* __restrict__ GATE,
    const float* __restrict__ W_out, const float* __restrict__ ln_w,
    const float* __restrict__ ln_b, const float* __restrict__ bo,
    float* __restrict__ out)
{
    __shared__ float fgT[256][64];              // 64 KiB, [channel][row]
    int tid = threadIdx.x;
    int m0 = blockIdx.x * 64;                   // 2048 blocks
    int r = tid >> 2, q = tid & 3;              // 4 threads per row
    size_t prow4 = (size_t)(m0 + r)*64 + q*16;  // float4 units (256 f32/row)
    size_t grow = (size_t)(m0 + r)*256;         // u16 units (in d_out)

    // gate, natural order: gate[pd] and gate[128+pd] for pd in [q*32, q*32+32)
    uint4 ga[4], gb[4];
    #pragma unroll
    for (int g4 = 0; g4 < 4; ++g4) {
        ga[g4] = *(const uint4*)(GATE + grow + q*32 + g4*8);
        gb[g4] = *(const uint4*)(GATE + grow + 128 + q*32 + g4*8);
    }

    float4 p4[16];
    #pragma unroll
    for (int c4 = 0; c4 < 16; ++c4) p4[c4] = Pf[prow4 + c4];

    float sum = 0.f, ss = 0.f;
    #pragma unroll
    for (int c4 = 0; c4 < 16; ++c4) {
        sum += p4[c4].x + p4[c4].y + p4[c4].z + p4[c4].w;
        ss  += p4[c4].x*p4[c4].x + p4[c4].y*p4[c4].y
             + p4[c4].z*p4[c4].z + p4[c4].w*p4[c4].w;
    }
    sum += __shfl_xor(sum, 1); sum += __shfl_xor(sum, 2);
    ss  += __shfl_xor(ss, 1);  ss  += __shfl_xor(ss, 2);
    float mu = sum * (1.f/256.f);
    float var = ss * (1.f/256.f) - mu*mu;
    float rstd = rsqrtf(var + 1e-5f);

    #pragma unroll
    for (int c4 = 0; c4 < 16; ++c4) {
        #pragma unroll
        for (int sub = 0; sub < 2; ++sub) {
            int jj = c4*2 + sub;                // 0..31
            int pd = q*32 + jj;                 // complex channel 0..127
            float fr = sub ? p4[c4].z : p4[c4].x;
            float fi = sub ? p4[c4].w : p4[c4].y;
            int g4 = jj >> 3, e = jj & 7;
            u32 gur = GETC(ga[g4], e>>1), gui = GETC(gb[g4], e>>1);
            float gvr = b2f((u16)((e&1) ? (gur>>16) : (gur&0xffff)));
            float gvi = b2f((u16)((e&1) ? (gui>>16) : (gui&0xffff)));
            float vr = ((fr - mu)*rstd*ln_w[pd]     + ln_b[pd])     * gvr;
            float vi = ((fi - mu)*rstd*ln_w[128+pd] + ln_b[128+pd]) * gvi;
            fgT[pd][r]     = vr;
            fgT[128+pd][r] = vi;
        }
    }
    __syncthreads();   // all GATE/P reads done before out writes (same bytes)

    // out[64][128] = fgT^T @ W_out  (f32 FMA, W_out read natively from global)
    int ri = tid >> 4, ci = tid & 15;
    #pragma unroll
    for (int n0 = 0; n0 < 128; n0 += 64) {
        float acc[4][4] = {};
        for (int k = 0; k < 256; ++k) {
            float4 xv = *(const float4*)(&fgT[k][ri*4]);
            float4 wv = *(const float4*)(W_out + (size_t)k*128 + n0 + ci*4);
            acc[0][0] = fmaf(xv.x, wv.x, acc[0][0]);
            acc[0][1] = fmaf(xv.x, wv.y, acc[0][1]);
            acc[0][2] = fmaf(xv.x, wv.z, acc[0][2]);
            acc[0][3] = fmaf(xv.x, wv.w, acc[0][3]);
            acc[1][0] = fmaf(xv.y, wv.x, acc[1][0]);
            acc[1][1] = fmaf(xv.y, wv.y, acc[1][1]);
            acc[1][2] = fmaf(xv.y, wv.z, acc[1][2]);
            acc[1][3] = fmaf(xv.y, wv.w, acc[1][3]);
            acc[2][0] = fmaf(xv.z, wv.x, acc[2][0]);
            acc[2][1] = fmaf(xv.z, wv.y, acc[2][1]);
            acc[2][2] = fmaf(xv.z, wv.z, acc[2][2]);
            acc[2][3] = fmaf(xv.z, wv.w, acc[2][3]);
            acc[3][0] = fmaf(xv.w, wv.x, acc[3][0]);
            acc[3][1] = fmaf(xv.w, wv.y, acc[3][1]);
            acc[3][2] = fmaf(xv.w, wv.z, acc[3][2]);
            acc[3][3] = fmaf(xv.w, wv.w, acc[3][3]);
        }
        #pragma unroll
        for (int i = 0; i < 4; ++i) {
            int m = m0 + ri*4 + i;
            #pragma unroll
            for (int j = 0; j < 4; ++j) {
                int n = n0 + ci*4 + j;
                out[(size_t)m*128 + n] = acc[i][j] + bo[n];
            }
        }
    }
}

// ---------------- launch -----------------------------------------------------
extern "C" void kernel_launch(void* const* d_in, const int* in_sizes, int n_in,
                              void* d_out, int out_size, void* d_ws, size_t ws_size,
                              hipStream_t stream)
{
    const float* x      = (const float*)d_in[0];
    const float* W_in   = (const float*)d_in[1];
    const float* b_in   = (const float*)d_in[2];
    const float* W_lam  = (const float*)d_in[3];
    const float* b_lam  = (const float*)d_in[4];
    const float* th_f   = (const float*)d_in[5];
    const float* th_r   = (const float*)d_in[6];
    const float* W_gate = (const float*)d_in[7];
    const float* b_gate = (const float*)d_in[8];
    const float* W_out  = (const float*)d_in[9];
    const float* b_out  = (const float*)d_in[10];
    const float* ln_w   = (const float*)d_in[11];
    const float* ln_b   = (const float*)d_in[12];

    // ws layout: 167,774,208 B <= 168,008,192 B proven-safe envelope
    char* ws = (char*)d_ws;
    float2* P  = (float2*)(ws);                   // 134,217,728 (f32 complex, full d)
    float* OMH = (float*)(ws + 134217728LL);      // 33,554,432 (f32 om, half d)
    float* trig= (float*)(ws + 167772160LL);      // 2,048

    // d_out time-shares: IH f32[M][128] (per half) -> GATE bf16[M][256] -> out f32
    float* IH = (float*)d_out;
    u16* GATE = (u16*)d_out;
    float* out = (float*)d_out;

    hipLaunchKernelGGL(k_prep, dim3(1), dim3(128), 0, stream, th_f, th_r, trig);

    // half 0
    hipLaunchKernelGGL(HIP_KERNEL_NAME(k_front_f32<0>), dim3(2048), dim3(256), 0, stream,
                       x, W_in, b_in, W_lam, b_lam, IH, OMH);
    hipLaunchKernelGGL(HIP_KERNEL_NAME(k_scan<0,0,0,0>), dim3(256), dim3(256), 0, stream, IH, OMH, trig, P);
    hipLaunchKernelGGL(HIP_KERNEL_NAME(k_scan<0,1,1,0>), dim3(256), dim3(256), 0, stream, IH, OMH, trig, P);
    hipLaunchKernelGGL(HIP_KERNEL_NAME(k_scan<1,0,1,0>), dim3(256), dim3(256), 0, stream, IH, OMH, trig, P);
    hipLaunchKernelGGL(HIP_KERNEL_NAME(k_scan<1,1,1,0>), dim3(256), dim3(256), 0, stream, IH, OMH, trig, P);

    // half 1 (reuses IH/OMH buffers)
    hipLaunchKernelGGL(HIP_KERNEL_NAME(k_front_f32<1>), dim3(2048), dim3(256), 0, stream,
                       x, W_in, b_in, W_lam, b_lam, IH, OMH);
    hipLaunchKernelGGL(HIP_KERNEL_NAME(k_scan<0,0,0,1>), dim3(256), dim3(256), 0, stream, IH, OMH, trig, P);
    hipLaunchKernelGGL(HIP_KERNEL_NAME(k_scan<0,1,1,1>), dim3(256), dim3(256), 0, stream, IH, OMH, trig, P);
    hipLaunchKernelGGL(HIP_KERNEL_NAME(k_scan<1,0,1,1>), dim3(256), dim3(256), 0, stream, IH, OMH, trig, P);
    hipLaunchKernelGGL(HIP_KERNEL_NAME(k_scan<1,1,1,1>), dim3(256), dim3(256), 0, stream, IH, OMH, trig, P);

    hipLaunchKernelGGL(k_gate_f32, dim3(2048), dim3(256), 0, stream,
                       x, W_gate, b_gate, GATE);
    hipLaunchKernelGGL(k_backend_f32, dim3(2048), dim3(256), 0, stream,
                       (const float4*)P, GATE, W_out, ln_w, ln_b, b_out, out);
}